// Round 17
// baseline (232.809 us; speedup 1.0000x reference)
//
#include <hip/hip_runtime.h>
#include <stdint.h>

// ---------------- constants ----------------
#define D_MODEL 1024
#define S_LEN   2048
#define NHEAD   16
#define HEAD_DIM 64
#define BATCH   2
#define M_TOT   (BATCH * S_LEN)   // 4096
#define Q_SCALE 0.18033688011112042f   // (1/sqrt(64)) * log2(e)

using bf16x8 = __attribute__((ext_vector_type(8))) short;
using f32x4  = __attribute__((ext_vector_type(4))) float;

__device__ __forceinline__ unsigned short f2bf(float f) {
  union { float f; unsigned int u; } v; v.f = f;
  unsigned int u = v.u;
  return (unsigned short)((u + 0x7FFFu + ((u >> 16) & 1u)) >> 16);
}
__device__ __forceinline__ unsigned int pkbf(float a, float b) {
#if __has_builtin(__builtin_amdgcn_cvt_pk_bf16_f32)
  auto p = __builtin_amdgcn_cvt_pk_bf16_f32(a, b);
  union { decltype(p) v; unsigned int u; } c; c.v = p;
  return c.u;
#else
  return (unsigned int)f2bf(a) | ((unsigned int)f2bf(b) << 16);
#endif
}
__device__ __forceinline__ bf16x8 cvt8(const float* p) {
  const float4 a = *(const float4*)p;
  const float4 b = *(const float4*)(p + 4);
  union { unsigned int u[4]; bf16x8 v; } r;
  r.u[0] = pkbf(a.x, a.y); r.u[1] = pkbf(a.z, a.w);
  r.u[2] = pkbf(b.x, b.y); r.u[3] = pkbf(b.z, b.w);
  return r.v;
}
__device__ __forceinline__ bf16x8 cvt8r(f32x4 a, f32x4 b) {
  union { unsigned int u[4]; bf16x8 v; } r;
  r.u[0] = pkbf(a[0], a[1]); r.u[1] = pkbf(a[2], a[3]);
  r.u[2] = pkbf(b[0], b[1]); r.u[3] = pkbf(b[2], b[3]);
  return r.v;
}
__device__ __forceinline__ float fexp2(float x) {
#if __has_builtin(__builtin_amdgcn_exp2f)
  return __builtin_amdgcn_exp2f(x);
#else
  return __expf(x * 0.69314718055994531f);
#endif
}
__device__ __forceinline__ void async16(const unsigned short* g, short* l) {
  __builtin_amdgcn_global_load_lds(
      reinterpret_cast<const __attribute__((address_space(1))) unsigned int*>(
          reinterpret_cast<uintptr_t>(g)),
      reinterpret_cast<__attribute__((address_space(3))) unsigned int*>(
          reinterpret_cast<uintptr_t>(l)),
      16, 0, 0);
}

// Counted waits (T4): inline-asm + sched_barrier fence (rule #18).
__device__ __forceinline__ void waitv0() {
  asm volatile("s_waitcnt vmcnt(0)" ::: "memory");
  __builtin_amdgcn_sched_barrier(0);
}
__device__ __forceinline__ void waitv1() {
  asm volatile("s_waitcnt vmcnt(1)" ::: "memory");
  __builtin_amdgcn_sched_barrier(0);
}
__device__ __forceinline__ void waitv2() {
  asm volatile("s_waitcnt vmcnt(2)" ::: "memory");
  __builtin_amdgcn_sched_barrier(0);
}
__device__ __forceinline__ void waitv3() {
  asm volatile("s_waitcnt vmcnt(3)" ::: "memory");
  __builtin_amdgcn_sched_barrier(0);
}
__device__ __forceinline__ void waitv4() {
  asm volatile("s_waitcnt vmcnt(4)" ::: "memory");
  __builtin_amdgcn_sched_barrier(0);
}
__device__ __forceinline__ void waitl0() {
  asm volatile("s_waitcnt lgkmcnt(0)" ::: "memory");
  __builtin_amdgcn_sched_barrier(0);
}

// Cross-lane half-swaps (gfx950 v_permlane{16,32}_swap_b32).
__device__ __forceinline__ void swap32(unsigned int& x, unsigned int& y) {
#if __has_builtin(__builtin_amdgcn_permlane32_swap)
  auto r = __builtin_amdgcn_permlane32_swap(x, y, false, false);
  x = (unsigned int)r[0]; y = (unsigned int)r[1];
#else
  const int lane = threadIdx.x & 63;
  unsigned int sx = (unsigned int)__shfl_xor((int)x, 32);
  unsigned int sy = (unsigned int)__shfl_xor((int)y, 32);
  unsigned int nx = (lane & 32) ? sy : x;
  unsigned int ny = (lane & 32) ? y : sx;
  x = nx; y = ny;
#endif
}
__device__ __forceinline__ void swap16(unsigned int& x, unsigned int& y) {
#if __has_builtin(__builtin_amdgcn_permlane16_swap)
  auto r = __builtin_amdgcn_permlane16_swap(x, y, false, false);
  x = (unsigned int)r[0]; y = (unsigned int)r[1];
#else
  const int lane = threadIdx.x & 63;
  unsigned int sx = (unsigned int)__shfl_xor((int)x, 16);
  unsigned int sy = (unsigned int)__shfl_xor((int)y, 16);
  unsigned int nx = (lane & 16) ? sy : x;
  unsigned int ny = (lane & 16) ? y : sx;
  x = nx; y = ny;
#endif
}

#define LDK 40   // padded stride for the slow (fp32-A) staging core

// ---------------- one-shot cast fp32 -> bf16 (WEIGHTS ONLY in fast path) -----
__global__ __launch_bounds__(256)
void cast_all(const float* __restrict__ wq, const float* __restrict__ wk,
              const float* __restrict__ wv, const float* __restrict__ wo,
              const float* __restrict__ q, const float* __restrict__ k,
              const float* __restrict__ v,
              unsigned short* __restrict__ wb,
              unsigned short* __restrict__ qb, unsigned short* __restrict__ kb,
              unsigned short* __restrict__ vb)
{
  const int z = blockIdx.y;
  const float* src;
  unsigned short* d;
  size_t n;
  switch (z) {
    case 0: src = wq; d = wb;                                   n = (size_t)D_MODEL * D_MODEL; break;
    case 1: src = wk; d = wb + (size_t)1 * D_MODEL * D_MODEL;   n = (size_t)D_MODEL * D_MODEL; break;
    case 2: src = wv; d = wb + (size_t)2 * D_MODEL * D_MODEL;   n = (size_t)D_MODEL * D_MODEL; break;
    case 3: src = wo; d = wb + (size_t)3 * D_MODEL * D_MODEL;   n = (size_t)D_MODEL * D_MODEL; break;
    case 4: src = q;  d = qb;                                   n = (size_t)M_TOT * D_MODEL;   break;
    case 5: src = k;  d = kb;                                   n = (size_t)M_TOT * D_MODEL;   break;
    default: src = v; d = vb;                                   n = (size_t)M_TOT * D_MODEL;   break;
  }
  const size_t i = ((size_t)blockIdx.x * 256 + threadIdx.x) * 8;
  if (i < n) *(bf16x8*)(d + i) = cvt8(src + i);
}

// --- 128x128 BK=32 core, 512 thr: fp32-A reg-staged (inline cast), W via ----
// --- gload_lds; counted-vmcnt 3-buffer pipeline + T2 XOR swizzle. -----------
// v21: folds the q/k/v bf16 cast into staging. Per stage (FIFO order A0,A1,W):
// steady state issue s(kt+2) -> vmcnt(4) [A(kt+1) landed] -> cvt+ds_write
// A(kt+1) -> lgkmcnt(0) [frag reads + ds_write, before raw barrier] -> MFMA ->
// vmcnt(3) [W(kt+1) landed] -> barrier. A-regs: named even/odd sets (rule #20).
#define QBUF (128 * 32)

__device__ __forceinline__ void gemm_tile_cvf(const float* __restrict__ A,
                                              const unsigned short* __restrict__ W,
                                              int m0, int n0,
                                              short* As, short* Bs,   // [3][128*32]
                                              f32x4 acc[4][2])
{
  const int t    = threadIdx.x;       // 0..511
  const int lane = t & 63;
  const int w    = t >> 6;            // 0..7
  const int quad = lane >> 4;
  const int l16  = lane & 15;
  const int wm   = (w >> 2) * 64;     // {0,64}
  const int wn   = (w & 3) * 32;      // {0,32,64,96}
  const int srow = t >> 2;            // 0..127
  const int sc   = t & 3;             // dest 16B chunk in row (linear)
  const int scg  = (sc ^ ((srow >> 1) & 3)) * 8;   // swizzled SOURCE col (elems)
  const int sdst = srow * 32 + sc * 8;             // LINEAR dest (shorts)
  const int rk   = (l16 >> 1) & 3;                 // read-side XOR key
  const int rq   = (quad ^ rk) * 8;                // swizzled read chunk

  const float*          Agf = A + (size_t)(m0 + srow) * D_MODEL + scg;
  const unsigned short* Wg  = W + (size_t)(n0 + srow) * D_MODEL + scg;

  for (int mt = 0; mt < 4; ++mt)
    for (int nt = 0; nt < 2; ++nt)
      acc[mt][nt] = f32x4{0.f, 0.f, 0.f, 0.f};

  // A-stage register double buffer (named sets; stage parity selects).
  f32x4 a0e, a1e, a0o, a1o;

  // Prologue: stage0 (even regs) + W0; stage1 (odd regs) + W1.
  a0e = *(const f32x4*)(Agf);
  a1e = *(const f32x4*)(Agf + 4);
  async16(Wg, Bs + sdst);
  a0o = *(const f32x4*)(Agf + 32);
  a1o = *(const f32x4*)(Agf + 36);
  async16(Wg + 32, Bs + QBUF + sdst);
  waitv4();                                  // stage0 A pair landed
  *(bf16x8*)(As + sdst) = cvt8r(a0e, a1e);   // write A0 -> buf0
  waitv3();                                  // W0 landed (A1 pair + W1 in flight)
  waitl0();                                  // ds_write drained
  __builtin_amdgcn_s_barrier();

  int rc = 0;                          // read buffer = kt % 3
  for (int kt = 0; kt < 32; ++kt) {
    const short* ab = As + rc * QBUF;
    const short* bb = Bs + rc * QBUF;
    bf16x8 af[4], bfr[2];
#pragma unroll
    for (int mt = 0; mt < 4; ++mt)
      af[mt] = *(const bf16x8*)(ab + (wm + mt * 16 + l16) * 32 + rq);
#pragma unroll
    for (int nt = 0; nt < 2; ++nt)
      bfr[nt] = *(const bf16x8*)(bb + (wn + nt * 16 + l16) * 32 + rq);

    const bool have_next = (kt + 1 < 32);
    const bool more      = (kt + 2 < 32);
    const int  wb1 = (rc + 1 == 3) ? 0 : rc + 1;            // (kt+1)%3
    const int  wb2 = (rc + 2 >= 3) ? rc - 1 : rc + 2;       // (kt+2)%3

    if (more) {
      const int kc = (kt + 2) * 32;
      if ((kt & 1) == 0) {             // stage kt+2 even -> even regs
        a0e = *(const f32x4*)(Agf + kc);
        a1e = *(const f32x4*)(Agf + kc + 4);
      } else {
        a0o = *(const f32x4*)(Agf + kc);
        a1o = *(const f32x4*)(Agf + kc + 4);
      }
      async16(Wg + kc, Bs + wb2 * QBUF + sdst);
    }

    if (have_next) {
      if (more) waitv4();              // A(kt+1) pair landed
      else      waitv1();              // tail: only W(kt+1) still in flight
      if ((kt & 1) == 0)               // stage kt+1 odd -> odd regs
        *(bf16x8*)(As + wb1 * QBUF + sdst) = cvt8r(a0o, a1o);
      else
        *(bf16x8*)(As + wb1 * QBUF + sdst) = cvt8r(a0e, a1e);
    }

    waitl0();   // frag reads in VGPRs + A ds_write drained (before barrier)

    __builtin_amdgcn_s_setprio(1);
#pragma unroll
    for (int mt = 0; mt < 4; ++mt)
#pragma unroll
      for (int nt = 0; nt < 2; ++nt)
        acc[mt][nt] = __builtin_amdgcn_mfma_f32_16x16x32_bf16(af[mt], bfr[nt], acc[mt][nt], 0, 0, 0);
    __builtin_amdgcn_s_setprio(0);

    if (kt < 31) {
      if (more) waitv3();              // W(kt+1) landed; stage kt+2 in flight
      else      waitv0();
      __builtin_amdgcn_s_barrier();
    }
    rc = (rc == 2) ? 0 : rc + 1;
  }
}

// ------- 64x128 BK=32 core, 256 thr, counted-vmcnt + T2 XOR swizzle ---------
#define OBA (64 * 32)
#define OBB (128 * 32)

__device__ __forceinline__ void gemm_tile_cv64(const unsigned short* __restrict__ A,
                                               const unsigned short* __restrict__ W,
                                               int m0, int n0,
                                               short* As, short* Bs,  // [3][..]
                                               f32x4 acc[2][4])
{
  const int t    = threadIdx.x;       // 0..255
  const int lane = t & 63;
  const int w    = t >> 6;            // 0..3
  const int quad = lane >> 4;
  const int l16  = lane & 15;
  const int wm   = (w >> 1) * 32;     // wave grid 2x2 over 64x128
  const int wn   = (w & 1) * 64;
  const int srow = t >> 2;            // 0..63
  const int sc   = t & 3;
  const int scg  = (sc ^ ((srow >> 1) & 3)) * 8;   // swizzled SOURCE col
  const int sdst = srow * 32 + sc * 8;             // LINEAR dest
  const int rk   = (l16 >> 1) & 3;
  const int rq   = (quad ^ rk) * 8;

  const unsigned short* Ag  = A + (size_t)(m0 + srow)      * D_MODEL + scg;
  const unsigned short* Wg0 = W + (size_t)(n0 + srow)      * D_MODEL + scg;
  const unsigned short* Wg1 = W + (size_t)(n0 + 64 + srow) * D_MODEL + scg;

  for (int mt = 0; mt < 2; ++mt)
    for (int nt = 0; nt < 4; ++nt)
      acc[mt][nt] = f32x4{0.f, 0.f, 0.f, 0.f};

  async16(Ag,       As + sdst);
  async16(Wg0,      Bs + sdst);
  async16(Wg1,      Bs + OBA + sdst);
  async16(Ag + 32,  As + OBA + sdst);
  async16(Wg0 + 32, Bs + OBB + sdst);
  async16(Wg1 + 32, Bs + OBB + OBA + sdst);
  waitv3();
  __builtin_amdgcn_s_barrier();

  int rc = 0;
  for (int kt = 0; kt < 32; ++kt) {
    const short* ab = As + rc * OBA;
    const short* bb = Bs + rc * OBB;
    bf16x8 af[2], bfr[4];
#pragma unroll
    for (int mt = 0; mt < 2; ++mt)
      af[mt] = *(const bf16x8*)(ab + (wm + mt * 16 + l16) * 32 + rq);
#pragma unroll
    for (int nt = 0; nt < 4; ++nt)
      bfr[nt] = *(const bf16x8*)(bb + (wn + nt * 16 + l16) * 32 + rq);

    const bool more = (kt + 2 < 32);
    if (more) {
      const int wcIdx = (rc + 2 >= 3) ? rc - 1 : rc + 2;
      const int kc = (kt + 2) * 32;
      async16(Ag + kc,  As + wcIdx * OBA + sdst);
      async16(Wg0 + kc, Bs + wcIdx * OBB + sdst);
      async16(Wg1 + kc, Bs + wcIdx * OBB + OBA + sdst);
    }

    waitl0();

    __builtin_amdgcn_s_setprio(1);
#pragma unroll
    for (int mt = 0; mt < 2; ++mt)
#pragma unroll
      for (int nt = 0; nt < 4; ++nt)
        acc[mt][nt] = __builtin_amdgcn_mfma_f32_16x16x32_bf16(af[mt], bfr[nt], acc[mt][nt], 0, 0, 0);
    __builtin_amdgcn_s_setprio(0);

    if (kt < 31) {
      if (more) waitv3();
      else      waitv0();
      __builtin_amdgcn_s_barrier();
    }
    rc = (rc == 2) ? 0 : rc + 1;
  }
}

// ---------------- slow GEMM core (fp32 A converted on the fly) ----------------
__device__ __forceinline__ void gemm_tile_f32(const float* __restrict__ A,
                                              const unsigned short* __restrict__ W,
                                              int m0, int n0,
                                              short* As, short* Bs,
                                              f32x4 acc[4][4])
{
  const int t    = threadIdx.x;
  const int lane = t & 63;
  const int w    = t >> 6;
  const int quad = lane >> 4;
  const int l16  = lane & 15;
  const int wm   = (w >> 1) * 64;
  const int wn   = (w & 1) * 64;
  const int srow = t >> 2;
  const int scol = (t & 3) * 8;

  for (int mt = 0; mt < 4; ++mt)
    for (int nt = 0; nt < 4; ++nt)
      acc[mt][nt] = f32x4{0.f, 0.f, 0.f, 0.f};

  for (int kt = 0; kt < D_MODEL / 32; ++kt) {
    const int kc = kt * 32 + scol;
    const bf16x8 a0 = cvt8(A + (size_t)(m0 + srow)      * D_MODEL + kc);
    const bf16x8 a1 = cvt8(A + (size_t)(m0 + srow + 64) * D_MODEL + kc);
    const bf16x8 b0 = *(const bf16x8*)(W + (size_t)(n0 + srow)      * D_MODEL + kc);
    const bf16x8 b1 = *(const bf16x8*)(W + (size_t)(n0 + srow + 64) * D_MODEL + kc);
    __syncthreads();
    *(bf16x8*)(As + (srow)      * LDK + scol) = a0;
    *(bf16x8*)(As + (srow + 64) * LDK + scol) = a1;
    *(bf16x8*)(Bs + (srow)      * LDK + scol) = b0;
    *(bf16x8*)(Bs + (srow + 64) * LDK + scol) = b1;
    __syncthreads();

    bf16x8 af[4], bfr[4];
    for (int mt = 0; mt < 4; ++mt)
      af[mt] = *(const bf16x8*)(As + (wm + mt * 16 + l16) * LDK + quad * 8);
    for (int nt = 0; nt < 4; ++nt)
      bfr[nt] = *(const bf16x8*)(Bs + (wn + nt * 16 + l16) * LDK + quad * 8);
    for (int mt = 0; mt < 4; ++mt)
      for (int nt = 0; nt < 4; ++nt)
        acc[mt][nt] = __builtin_amdgcn_mfma_f32_16x16x32_bf16(af[mt], bfr[nt], acc[mt][nt], 0, 0, 0);
  }
}

// ---------------- QKV epilogue for the 8-wave 128x128 core -------------------
__device__ __forceinline__ void qkv_epilogue8w(int z, int m0, int n0,
                                               const float* __restrict__ bias,
                                               float scale,
                                               unsigned short* __restrict__ dst,
                                               f32x4 acc[4][2])
{
  const int t    = threadIdx.x;
  const int lane = t & 63;
  const int w    = t >> 6;
  const int quad = lane >> 4;
  const int l16  = lane & 15;
  const int wm   = (w >> 2) * 64;
  const int wn   = (w & 3) * 32;

  for (int nt = 0; nt < 2; ++nt) {
    const int n = n0 + wn + nt * 16 + l16;
    const float bb = bias[n];
    const int h = n >> 6, d = n & 63;
    for (int mt = 0; mt < 4; ++mt) {
      for (int r = 0; r < 4; ++r) {
        const int m = m0 + wm + mt * 16 + quad * 4 + r;
        const int b = m >> 11, s = m & 2047;
        const unsigned short val = f2bf((acc[mt][nt][r] + bb) * scale);
        if (z < 2)
          dst[((size_t)((b * NHEAD + h) * S_LEN + s)) * HEAD_DIM + d] = val;
        else
          dst[((size_t)((b * NHEAD + h) * HEAD_DIM + d)) * S_LEN + s] = val;
      }
    }
  }
}

// ---------------- QKV projection, fast (fp32 inputs, fused cast) -------------
__global__ __launch_bounds__(512)
void qkv_fast(const float* __restrict__ q, const float* __restrict__ k,
              const float* __restrict__ v,
              const unsigned short* __restrict__ wqb,
              const unsigned short* __restrict__ wkb,
              const unsigned short* __restrict__ wvb,
              const float* __restrict__ bq, const float* __restrict__ bk,
              const float* __restrict__ bv,
              unsigned short* __restrict__ Qh, unsigned short* __restrict__ Kh,
              unsigned short* __restrict__ VhT)
{
  __shared__ __attribute__((aligned(16))) short As[3 * QBUF];
  __shared__ __attribute__((aligned(16))) short Bs[3 * QBUF];
  const int z = blockIdx.z;
  const float*          A    = (z == 0) ? q   : (z == 1) ? k   : v;
  const unsigned short* W    = (z == 0) ? wqb : (z == 1) ? wkb : wvb;
  const float*          bias = (z == 0) ? bq  : (z == 1) ? bk  : bv;
  unsigned short*       dst  = (z == 0) ? Qh  : (z == 1) ? Kh  : VhT;
  const float           scale = (z == 0) ? Q_SCALE : 1.0f;

  const int m0 = blockIdx.x * 128, n0 = blockIdx.y * 128;
  f32x4 acc[4][2];
  gemm_tile_cvf(A, W, m0, n0, As, Bs, acc);
  qkv_epilogue8w(z, m0, n0, bias, scale, dst, acc);
}

// ---------------- QKV projection, slow (fp32 inputs) ----------------
__global__ __launch_bounds__(256)
void qkv_slow(const float* __restrict__ query, const float* __restrict__ key,
              const float* __restrict__ value,
              const unsigned short* __restrict__ wqb,
              const unsigned short* __restrict__ wkb,
              const unsigned short* __restrict__ wvb,
              const float* __restrict__ bq, const float* __restrict__ bk,
              const float* __restrict__ bv,
              unsigned short* __restrict__ Qh, unsigned short* __restrict__ Kh,
              unsigned short* __restrict__ VhT)
{
  __shared__ __attribute__((aligned(16))) short As[128 * LDK];
  __shared__ __attribute__((aligned(16))) short Bs[128 * LDK];
  const int z = blockIdx.z;
  const float*          A    = (z == 0) ? query : (z == 1) ? key : value;
  const unsigned short* W    = (z == 0) ? wqb   : (z == 1) ? wkb : wvb;
  const float*          bias = (z == 0) ? bq    : (z == 1) ? bk  : bv;
  unsigned short*       dst  = (z == 0) ? Qh    : (z == 1) ? Kh  : VhT;
  const float           scale = (z == 0) ? Q_SCALE : 1.0f;

  const int m0 = blockIdx.x * 128, n0 = blockIdx.y * 128;
  f32x4 acc[4][4];
  gemm_tile_f32(A, W, m0, n0, As, Bs, acc);

  const int t    = threadIdx.x;
  const int lane = t & 63;
  const int w    = t >> 6;
  const int quad = lane >> 4;
  const int l16  = lane & 15;
  const int wm   = (w >> 1) * 64;
  const int wn   = (w & 1) * 64;
  for (int nt = 0; nt < 4; ++nt) {
    const int n = n0 + wn + nt * 16 + l16;
    const float bb = bias[n];
    const int h = n >> 6, d = n & 63;
    for (int mt = 0; mt < 4; ++mt) {
      for (int r = 0; r < 4; ++r) {
        const int m = m0 + wm + mt * 16 + quad * 4 + r;
        const int b = m >> 11, s = m & 2047;
        const unsigned short val = f2bf((acc[mt][nt][r] + bb) * scale);
        if (z < 2)
          dst[((size_t)((b * NHEAD + h) * S_LEN + s)) * HEAD_DIM + d] = val;
        else
          dst[((size_t)((b * NHEAD + h) * HEAD_DIM + d)) * S_LEN + s] = val;
      }
    }
  }
}

// ---------------- output projection: 64x128, counted-vmcnt + swizzle ---------
__global__ __launch_bounds__(256)
void out_proj(const unsigned short* __restrict__ Oh,
              const unsigned short* __restrict__ wob,
              const float* __restrict__ bo,
              float* __restrict__ dst)
{
  __shared__ __attribute__((aligned(16))) short As[3 * OBA];
  __shared__ __attribute__((aligned(16))) short Bs[3 * OBB];
  const int m0 = blockIdx.x * 64, n0 = blockIdx.y * 128;
  f32x4 acc[2][4];
  gemm_tile_cv64(Oh, wob, m0, n0, As, Bs, acc);

  const int t    = threadIdx.x;
  const int lane = t & 63;
  const int w    = t >> 6;
  const int quad = lane >> 4;
  const int l16  = lane & 15;
  const int wm   = (w >> 1) * 32;
  const int wn   = (w & 1) * 64;

  for (int nt = 0; nt < 4; ++nt) {
    const int n = n0 + wn + nt * 16 + l16;
    const float bb = bo[n];
    for (int mt = 0; mt < 2; ++mt)
      for (int r = 0; r < 4; ++r) {
        const int m = m0 + wm + mt * 16 + quad * 4 + r;
        dst[(size_t)m * D_MODEL + n] = acc[mt][nt][r] + bb;
      }
  }
}

// ---------------- causal flash attention v16: balanced qt pairing ------------
// The measured-best attn: 8-wave dbuf, T14 issue-early staging, setprio,
// swapped QK^T with in-register P transpose.
struct Frags { bf16x8 ka0, ka1, kb0, kb1, v0, v1, v2, v3; };
struct StageRegs { bf16x8 k0, k1, v0, v1; };

#define KS_LD 72    // padded stride (shorts) for Ks rows
#define VT_LD 136   // padded stride (shorts) for Vts rows

__device__ __forceinline__ StageRegs load_stage(const unsigned short* __restrict__ Kb,
                                                const unsigned short* __restrict__ Vb,
                                                int k0, int kr, int kc, int vd, int vc) {
  StageRegs r;
  r.k0 = *(const bf16x8*)(Kb + (size_t)(k0 + kr)      * HEAD_DIM + kc);
  r.k1 = *(const bf16x8*)(Kb + (size_t)(k0 + kr + 64) * HEAD_DIM + kc);
  r.v0 = *(const bf16x8*)(Vb + (size_t)(vd)      * S_LEN + k0 + vc);
  r.v1 = *(const bf16x8*)(Vb + (size_t)(vd + 32) * S_LEN + k0 + vc);
  return r;
}
__device__ __forceinline__ void write_stage(const StageRegs& r, short* Ks, short* Vts,
                                            int kr, int kc, int vd, int vc) {
  *(bf16x8*)(Ks + (kr)      * KS_LD + kc) = r.k0;
  *(bf16x8*)(Ks + (kr + 64) * KS_LD + kc) = r.k1;
  *(bf16x8*)(Vts + (vd)      * VT_LD + vc) = r.v0;
  *(bf16x8*)(Vts + (vd + 32) * VT_LD + vc) = r.v1;
}
__device__ __forceinline__ Frags lds_frags(const short* Ks, const short* Vts,
                                           int c, int quad, int l16) {
  Frags f;
  const short* kp = Ks + (c * 32 + l16) * KS_LD + quad * 8;
  f.ka0 = *(const bf16x8*)(kp);
  f.ka1 = *(const bf16x8*)(kp + 32);
  f.kb0 = *(const bf16x8*)(kp + 16 * KS_LD);
  f.kb1 = *(const bf16x8*)(kp + 16 * KS_LD + 32);
  const short* vp = Vts + l16 * VT_LD + c * 32 + quad * 8;
  f.v0 = *(const bf16x8*)(vp);
  f.v1 = *(const bf16x8*)(vp + 16 * VT_LD);
  f.v2 = *(const bf16x8*)(vp + 32 * VT_LD);
  f.v3 = *(const bf16x8*)(vp + 48 * VT_LD);
  return f;
}

// One 32-k chunk for a 16-row wave. Swapped QK^T: s0/s1 hold k-halves
// [c0..c0+15] / [c0+16..c0+31] x q=l16. MODE: 0 = full; 1 = diag even-wave
// (s0 masked k<=q, s1 all-zero, its MFMAs skipped); 2 = diag odd-wave
// (s0 full, s1 masked). Masked predicate in both diag modes: quad*4+r <= l16.
template <int MODE>
__device__ __forceinline__ void proc_chunk(const Frags& f, const bf16x8 qf[2],
                                           const bf16x8& ones, int quad, int l16,
                                           f32x4& lacc, f32x4 oacc[4]) {
  f32x4 s0 = f32x4{0.f, 0.f, 0.f, 0.f};
  f32x4 s1 = f32x4{0.f, 0.f, 0.f, 0.f};
  __builtin_amdgcn_s_setprio(1);
  s0 = __builtin_amdgcn_mfma_f32_16x16x32_bf16(f.ka0, qf[0], s0, 0, 0, 0);
  s0 = __builtin_amdgcn_mfma_f32_16x16x32_bf16(f.ka1, qf[1], s0, 0, 0, 0);
  if (MODE != 1) {
    s1 = __builtin_amdgcn_mfma_f32_16x16x32_bf16(f.kb0, qf[0], s1, 0, 0, 0);
    s1 = __builtin_amdgcn_mfma_f32_16x16x32_bf16(f.kb1, qf[1], s1, 0, 0, 0);
  }
  __builtin_amdgcn_s_setprio(0);

  float st0[4], st1[4];
  const int kl = quad * 4;
#pragma unroll
  for (int r = 0; r < 4; ++r) {
    if (MODE == 0) {
      st0[r] = fexp2(s0[r]);
      st1[r] = fexp2(s1[r]);
    } else if (MODE == 1) {
      st0[r] = (kl + r <= l16) ? fexp2(s0[r]) : 0.f;
      st1[r] = 0.f;
    } else {
      st0[r] = fexp2(s0[r]);
      st1[r] = (kl + r <= l16) ? fexp2(s1[r]) : 0.f;
    }
  }

  // A-frag: P[q=l16][k = c0 + quad*8 + 0..7]  (verified pack+swap net)
  unsigned int a = pkbf(st0[0], st0[1]), b = pkbf(st0[2], st0[3]);
  unsigned int c = pkbf(st1[0], st1[1]), e = pkbf(st1[2], st1[3]);
  swap32(a, c); swap32(b, e);
  swap16(a, c); swap16(b, e);
  union { unsigned int u[4]; bf16x8 v; } pf;
  pf.u[0] = a; pf.u[1] = b; pf.u[2] = c; pf.u[3] = e;

  __builtin_amdgcn_s_setprio(1);
  lacc = __builtin_amdgcn_mfma_f32_16x16x32_bf16(pf.v, ones, lacc, 0, 0, 0);
  oacc[0] = __builtin_amdgcn_mfma_f32_16x16x32_bf16(pf.v, f.v0, oacc[0], 0, 0, 0);
  oacc[1] = __builtin_amdgcn_mfma_f32_16x16x32_bf16(pf.v, f.v1, oacc[1], 0, 0, 0);
  oacc[2] = __builtin_amdgcn_mfma_f32_16x16x32_bf16(pf.v, f.v2, oacc[2], 0, 0, 0);
  oacc[3] = __builtin_amdgcn_mfma_f32_16x16x32_bf16(pf.v, f.v3, oacc[3], 0, 0, 0);
  __builtin_amdgcn_s_setprio(0);
}

__global__ __launch_bounds__(512, 4)
void attn_kernel(const unsigned short* __restrict__ Qh,
                 const unsigned short* __restrict__ Kh,
                 const unsigned short* __restrict__ VhT,
                 unsigned short* __restrict__ O)
{
  __shared__ __attribute__((aligned(16))) short Ks[2][128 * KS_LD];
  __shared__ __attribute__((aligned(16))) short Vts[2][64 * VT_LD];

  // XCD swizzle (4 heads/XCD) + balanced qt map: qt(i) + qt(i+256) = 15.
  const int orig = blockIdx.x;
  const int xcd  = orig & 7;
  const int li   = orig >> 3;          // 0..63
  const int bh   = xcd * 4 + (li & 3);
  const int j16  = li >> 2;            // 0..15
  const int qt   = (j16 < 8) ? (15 - j16) : (j16 - 8);
  const int q0   = qt * 128;
  const int b    = bh >> 4;
  const int h    = bh & 15;
  const int t    = threadIdx.x;        // 0..511
  const int w    = t >> 6;             // 0..7 (wave id)
  const int lane = t & 63;
  const int quad = lane >> 4;
  const int l16  = lane & 15;
  const int rowbase = q0 + w * 16;     // wave owns 16 q-rows

  const unsigned short* Kb = Kh + (size_t)bh * S_LEN * HEAD_DIM;
  const unsigned short* Vb = VhT + (size_t)bh * HEAD_DIM * S_LEN;
  const int kr = t >> 3, kc = (t & 7) * 8;     // K staging: 512 thr x 2 rows
  const int vd = t >> 4, vc = (t & 15) * 8;    // V staging: 512 thr x 2 rows

  bf16x8 qf[2];
  {
    const size_t qrow = (size_t)bh * S_LEN + rowbase + l16;
    qf[0] = *(const bf16x8*)(Qh + qrow * HEAD_DIM + quad * 8);
    qf[1] = *(const bf16x8*)(Qh + qrow * HEAD_DIM + 32 + quad * 8);
  }
  bf16x8 ones;
#pragma unroll
  for (int j = 0; j < 8; ++j) ones[j] = (short)0x3F80;

  f32x4 lacc = f32x4{0.f, 0.f, 0.f, 0.f};
  f32x4 oacc[4];
#pragma unroll
  for (int dt = 0; dt < 4; ++dt) oacc[dt] = f32x4{0.f, 0.f, 0.f, 0.f};

  // Tiles 0..qt of 128 k. Tile j<qt: 4 full chunks. Tile qt: wave w does
  // (w>>1) full chunks + 1 diag chunk (mode by parity of w).
  const int nT = qt + 1;
  const int cw = w >> 1;
  const bool odd = (w & 1) != 0;

  StageRegs rs = load_stage(Kb, Vb, 0, kr, kc, vd, vc);
  write_stage(rs, Ks[0], Vts[0], kr, kc, vd, vc);
  __syncthreads();
  for (int j = 0; j < nT; ++j) {
    const short* Ksj = (j & 1) ? Ks[1] : Ks[0];
    const short* Vtj = (j & 1) ? Vts[1] : Vts[0];
    short* Ksn = (j & 1) ? Ks[0] : Ks[1];
    short* Vtn = (j & 1) ? Vts[0] : Vts[1];
    const bool more = (j + 1 < nT);
    if (more) rs = load_stage(Kb, Vb, (j + 1) * 128, kr, kc, vd, vc);  // T14
    if (j < qt) {
#pragma unroll
      for (int c = 0; c < 4; ++c) {
        const Frags f = lds_frags(Ksj, Vtj, c, quad, l16);
        proc_chunk<0>(f, qf, ones, quad, l16, lacc, oacc);
      }
    } else {
      for (int c = 0; c < cw; ++c) {         // wave-uniform bound
        const Frags f = lds_frags(Ksj, Vtj, c, quad, l16);
        proc_chunk<0>(f, qf, ones, quad, l16, lacc, oacc);
      }
      const Frags f = lds_frags(Ksj, Vtj, cw, quad, l16);
      if (odd) proc_chunk<2>(f, qf, ones, quad, l16, lacc, oacc);
      else     proc_chunk<1>(f, qf, ones, quad, l16, lacc, oacc);
    }
    if (more) write_stage(rs, Ksn, Vtn, kr, kc, vd, vc);
    __syncthreads();
  }

#pragma unroll
  for (int dt = 0; dt < 4; ++dt)
#pragma unroll
    for (int r = 0; r < 4; ++r) {
      const int rowg = rowbase + quad * 4 + r;
      O[(size_t)(b * S_LEN + rowg) * D_MODEL + h * 64 + dt * 16 + l16] =
          f2bf(oacc[dt][r] / lacc[r]);
    }
}

// ---------------- launcher ----------------
// ws layout: [0,8M) wqb|wkb|wvb|wob ; [8,16M) Kh ; [16,24M) VhT ; [24,32M) Oh.
// Fast path no longer pre-casts q/k/v (fused into qkv staging).
extern "C" void kernel_launch(void* const* d_in, const int* in_sizes, int n_in,
                              void* d_out, int out_size, void* d_ws, size_t ws_size,
                              hipStream_t stream)
{
  (void)in_sizes; (void)n_in; (void)out_size;
  const float* q  = (const float*)d_in[0];
  const float* k  = (const float*)d_in[1];
  const float* v  = (const float*)d_in[2];
  const float* wq = (const float*)d_in[3];
  const float* bq = (const float*)d_in[4];
  const float* wk = (const float*)d_in[5];
  const float* bk = (const float*)d_in[6];
  const float* wv = (const float*)d_in[7];
  const float* bv = (const float*)d_in[8];
  const float* wo = (const float*)d_in[9];
  const float* bo = (const float*)d_in[10];
  float* out = (float*)d_out;

  unsigned short* wb  = (unsigned short*)d_ws;
  unsigned short* wqb = wb;
  unsigned short* wkb = wb + (size_t)1 * D_MODEL * D_MODEL;
  unsigned short* wvb = wb + (size_t)2 * D_MODEL * D_MODEL;
  unsigned short* wob = wb + (size_t)3 * D_MODEL * D_MODEL;
  unsigned short* Kh  = wb + (size_t)4 * D_MODEL * D_MODEL;
  unsigned short* VhT = Kh + (size_t)M_TOT * D_MODEL;
  unsigned short* Oh  = VhT + (size_t)M_TOT * D_MODEL;
  unsigned short* qb  = Oh;                                  // unused (fast)
  unsigned short* vb  = Oh + (size_t)M_TOT * D_MODEL;        // unused (fast)
  unsigned short* Qh  = (unsigned short*)d_out;
  unsigned short* kb  = Qh + (size_t)M_TOT * D_MODEL;        // unused (fast)

  const bool fast = ws_size >= (size_t)40 * 1024 * 1024;

  // Weights-only cast (4 x 1M elems).
  dim3 gc((size_t)D_MODEL * D_MODEL / (256 * 8), 4, 1);
  cast_all<<<gc, 256, 0, stream>>>(wq, wk, wv, wo, q, k, v, wb, qb, kb, vb);

  dim3 g1(M_TOT / 128, D_MODEL / 128, 3);
  if (fast) {
    qkv_fast<<<g1, 512, 0, stream>>>(q, k, v, wqb, wkb, wvb, bq, bk, bv, Qh, Kh, VhT);
  } else {
    qkv_slow<<<g1, 256, 0, stream>>>(q, k, v, wqb, wkb, wvb, bq, bk, bv, Qh, Kh, VhT);
  }

  dim3 g2(512, 1, 1);
  attn_kernel<<<g2, 512, 0, stream>>>(Qh, Kh, VhT, Oh);

  dim3 g3(M_TOT / 64, D_MODEL / 128, 1);
  out_proj<<<g3, 256, 0, stream>>>(Oh, wob, bo, out);
}

// Round 18
// 205.196 us; speedup vs baseline: 1.1346x; 1.1346x over previous
//
#include <hip/hip_runtime.h>
#include <stdint.h>

// ---------------- constants ----------------
#define D_MODEL 1024
#define S_LEN   2048
#define NHEAD   16
#define HEAD_DIM 64
#define BATCH   2
#define M_TOT   (BATCH * S_LEN)   // 4096
#define Q_SCALE 0.18033688011112042f   // (1/sqrt(64)) * log2(e)

using bf16x8 = __attribute__((ext_vector_type(8))) short;
using f32x4  = __attribute__((ext_vector_type(4))) float;

__device__ __forceinline__ unsigned short f2bf(float f) {
  union { float f; unsigned int u; } v; v.f = f;
  unsigned int u = v.u;
  return (unsigned short)((u + 0x7FFFu + ((u >> 16) & 1u)) >> 16);
}
__device__ __forceinline__ unsigned int pkbf(float a, float b) {
#if __has_builtin(__builtin_amdgcn_cvt_pk_bf16_f32)
  auto p = __builtin_amdgcn_cvt_pk_bf16_f32(a, b);
  union { decltype(p) v; unsigned int u; } c; c.v = p;
  return c.u;
#else
  return (unsigned int)f2bf(a) | ((unsigned int)f2bf(b) << 16);
#endif
}
__device__ __forceinline__ bf16x8 cvt8(const float* p) {
  const float4 a = *(const float4*)p;
  const float4 b = *(const float4*)(p + 4);
  union { unsigned int u[4]; bf16x8 v; } r;
  r.u[0] = pkbf(a.x, a.y); r.u[1] = pkbf(a.z, a.w);
  r.u[2] = pkbf(b.x, b.y); r.u[3] = pkbf(b.z, b.w);
  return r.v;
}
__device__ __forceinline__ float fexp2(float x) {
#if __has_builtin(__builtin_amdgcn_exp2f)
  return __builtin_amdgcn_exp2f(x);
#else
  return __expf(x * 0.69314718055994531f);
#endif
}
__device__ __forceinline__ void async16(const unsigned short* g, short* l) {
  __builtin_amdgcn_global_load_lds(
      reinterpret_cast<const __attribute__((address_space(1))) unsigned int*>(
          reinterpret_cast<uintptr_t>(g)),
      reinterpret_cast<__attribute__((address_space(3))) unsigned int*>(
          reinterpret_cast<uintptr_t>(l)),
      16, 0, 0);
}

// Counted waits (T4): inline-asm + sched_barrier fence (rule #18).
__device__ __forceinline__ void waitv2() {
  asm volatile("s_waitcnt vmcnt(2)" ::: "memory");
  __builtin_amdgcn_sched_barrier(0);
}
__device__ __forceinline__ void waitv3() {
  asm volatile("s_waitcnt vmcnt(3)" ::: "memory");
  __builtin_amdgcn_sched_barrier(0);
}
__device__ __forceinline__ void waitv0() {
  asm volatile("s_waitcnt vmcnt(0)" ::: "memory");
  __builtin_amdgcn_sched_barrier(0);
}
__device__ __forceinline__ void waitl0() {
  asm volatile("s_waitcnt lgkmcnt(0)" ::: "memory");
  __builtin_amdgcn_sched_barrier(0);
}

// Cross-lane half-swaps (gfx950 v_permlane{16,32}_swap_b32).
__device__ __forceinline__ void swap32(unsigned int& x, unsigned int& y) {
#if __has_builtin(__builtin_amdgcn_permlane32_swap)
  auto r = __builtin_amdgcn_permlane32_swap(x, y, false, false);
  x = (unsigned int)r[0]; y = (unsigned int)r[1];
#else
  const int lane = threadIdx.x & 63;
  unsigned int sx = (unsigned int)__shfl_xor((int)x, 32);
  unsigned int sy = (unsigned int)__shfl_xor((int)y, 32);
  unsigned int nx = (lane & 32) ? sy : x;
  unsigned int ny = (lane & 32) ? y : sx;
  x = nx; y = ny;
#endif
}
__device__ __forceinline__ void swap16(unsigned int& x, unsigned int& y) {
#if __has_builtin(__builtin_amdgcn_permlane16_swap)
  auto r = __builtin_amdgcn_permlane16_swap(x, y, false, false);
  x = (unsigned int)r[0]; y = (unsigned int)r[1];
#else
  const int lane = threadIdx.x & 63;
  unsigned int sx = (unsigned int)__shfl_xor((int)x, 16);
  unsigned int sy = (unsigned int)__shfl_xor((int)y, 16);
  unsigned int nx = (lane & 16) ? sy : x;
  unsigned int ny = (lane & 16) ? y : sx;
  x = nx; y = ny;
#endif
}

#define LDK 40   // padded stride for the slow (fp32-A) staging core

// ---------------- fused one-shot casts fp32 -> bf16 ----------------
__global__ __launch_bounds__(256)
void cast_all(const float* __restrict__ wq, const float* __restrict__ wk,
              const float* __restrict__ wv, const float* __restrict__ wo,
              const float* __restrict__ q, const float* __restrict__ k,
              const float* __restrict__ v,
              unsigned short* __restrict__ wb,
              unsigned short* __restrict__ qb, unsigned short* __restrict__ kb,
              unsigned short* __restrict__ vb)
{
  const int z = blockIdx.y;
  const float* src;
  unsigned short* d;
  size_t n;
  switch (z) {
    case 0: src = wq; d = wb;                                   n = (size_t)D_MODEL * D_MODEL; break;
    case 1: src = wk; d = wb + (size_t)1 * D_MODEL * D_MODEL;   n = (size_t)D_MODEL * D_MODEL; break;
    case 2: src = wv; d = wb + (size_t)2 * D_MODEL * D_MODEL;   n = (size_t)D_MODEL * D_MODEL; break;
    case 3: src = wo; d = wb + (size_t)3 * D_MODEL * D_MODEL;   n = (size_t)D_MODEL * D_MODEL; break;
    case 4: src = q;  d = qb;                                   n = (size_t)M_TOT * D_MODEL;   break;
    case 5: src = k;  d = kb;                                   n = (size_t)M_TOT * D_MODEL;   break;
    default: src = v; d = vb;                                   n = (size_t)M_TOT * D_MODEL;   break;
  }
  const size_t i = ((size_t)blockIdx.x * 256 + threadIdx.x) * 8;
  if (i < n) *(bf16x8*)(d + i) = cvt8(src + i);
}

// ------- 128x128 BK=32 core, 512 thr, counted-vmcnt + T2 XOR swizzle --------
// Measured 43.2 us (v17): T4 pipeline + both-sides chunk XOR (conflicts -> 0).
#define QBUF (128 * 32)

__device__ __forceinline__ void gemm_tile_cv(const unsigned short* __restrict__ A,
                                             const unsigned short* __restrict__ W,
                                             int m0, int n0,
                                             short* As, short* Bs,   // [3][128*32]
                                             f32x4 acc[4][2])
{
  const int t    = threadIdx.x;       // 0..511
  const int lane = t & 63;
  const int w    = t >> 6;            // 0..7
  const int quad = lane >> 4;
  const int l16  = lane & 15;
  const int wm   = (w >> 2) * 64;     // {0,64}
  const int wn   = (w & 3) * 32;      // {0,32,64,96}
  const int srow = t >> 2;            // 0..127
  const int sc   = t & 3;             // dest 16B chunk in row (linear)
  const int scg  = (sc ^ ((srow >> 1) & 3)) * 8;   // swizzled SOURCE col
  const int sdst = srow * 32 + sc * 8;             // LINEAR dest
  const int rk   = (l16 >> 1) & 3;                 // read-side XOR key
  const int rq   = (quad ^ rk) * 8;                // swizzled read chunk

  const unsigned short* Ag = A + (size_t)(m0 + srow) * D_MODEL + scg;
  const unsigned short* Wg = W + (size_t)(n0 + srow) * D_MODEL + scg;

  for (int mt = 0; mt < 4; ++mt)
    for (int nt = 0; nt < 2; ++nt)
      acc[mt][nt] = f32x4{0.f, 0.f, 0.f, 0.f};

  // Prologue: stage kt=0 -> buf0, kt=1 -> buf1; wait S0 (S1 in flight).
  async16(Ag,      As + sdst);
  async16(Wg,      Bs + sdst);
  async16(Ag + 32, As + QBUF + sdst);
  async16(Wg + 32, Bs + QBUF + sdst);
  waitv2();
  __builtin_amdgcn_s_barrier();

  int rc = 0;                          // read buffer = kt % 3
  for (int kt = 0; kt < 32; ++kt) {
    const short* ab = As + rc * QBUF;
    const short* bb = Bs + rc * QBUF;
    bf16x8 af[4], bfr[2];
#pragma unroll
    for (int mt = 0; mt < 4; ++mt)
      af[mt] = *(const bf16x8*)(ab + (wm + mt * 16 + l16) * 32 + rq);
#pragma unroll
    for (int nt = 0; nt < 2; ++nt)
      bfr[nt] = *(const bf16x8*)(bb + (wn + nt * 16 + l16) * 32 + rq);

    const bool more = (kt + 2 < 32);
    if (more) {
      const int wcIdx = (rc + 2 >= 3) ? rc - 1 : rc + 2;   // (kt+2)%3
      const int kc = (kt + 2) * 32;
      async16(Ag + kc, As + wcIdx * QBUF + sdst);
      async16(Wg + kc, Bs + wcIdx * QBUF + sdst);
    }

    waitl0();   // frag reads landed in VGPRs

    __builtin_amdgcn_s_setprio(1);
#pragma unroll
    for (int mt = 0; mt < 4; ++mt)
#pragma unroll
      for (int nt = 0; nt < 2; ++nt)
        acc[mt][nt] = __builtin_amdgcn_mfma_f32_16x16x32_bf16(af[mt], bfr[nt], acc[mt][nt], 0, 0, 0);
    __builtin_amdgcn_s_setprio(0);

    if (kt < 31) {
      if (more) waitv2();   // stage kt+1 complete; kt+2 stays in flight
      else      waitv0();
      __builtin_amdgcn_s_barrier();
    }
    rc = (rc == 2) ? 0 : rc + 1;
  }
}

// ------- 64x128 BK=32 core, 256 thr, counted-vmcnt + T2 XOR swizzle ---------
#define OBA (64 * 32)
#define OBB (128 * 32)

__device__ __forceinline__ void gemm_tile_cv64(const unsigned short* __restrict__ A,
                                               const unsigned short* __restrict__ W,
                                               int m0, int n0,
                                               short* As, short* Bs,  // [3][..]
                                               f32x4 acc[2][4])
{
  const int t    = threadIdx.x;       // 0..255
  const int lane = t & 63;
  const int w    = t >> 6;            // 0..3
  const int quad = lane >> 4;
  const int l16  = lane & 15;
  const int wm   = (w >> 1) * 32;     // wave grid 2x2 over 64x128
  const int wn   = (w & 1) * 64;
  const int srow = t >> 2;            // 0..63
  const int sc   = t & 3;
  const int scg  = (sc ^ ((srow >> 1) & 3)) * 8;   // swizzled SOURCE col
  const int sdst = srow * 32 + sc * 8;             // LINEAR dest
  const int rk   = (l16 >> 1) & 3;
  const int rq   = (quad ^ rk) * 8;

  const unsigned short* Ag  = A + (size_t)(m0 + srow)      * D_MODEL + scg;
  const unsigned short* Wg0 = W + (size_t)(n0 + srow)      * D_MODEL + scg;
  const unsigned short* Wg1 = W + (size_t)(n0 + 64 + srow) * D_MODEL + scg;

  for (int mt = 0; mt < 2; ++mt)
    for (int nt = 0; nt < 4; ++nt)
      acc[mt][nt] = f32x4{0.f, 0.f, 0.f, 0.f};

  async16(Ag,       As + sdst);
  async16(Wg0,      Bs + sdst);
  async16(Wg1,      Bs + OBA + sdst);
  async16(Ag + 32,  As + OBA + sdst);
  async16(Wg0 + 32, Bs + OBB + sdst);
  async16(Wg1 + 32, Bs + OBB + OBA + sdst);
  waitv3();
  __builtin_amdgcn_s_barrier();

  int rc = 0;
  for (int kt = 0; kt < 32; ++kt) {
    const short* ab = As + rc * OBA;
    const short* bb = Bs + rc * OBB;
    bf16x8 af[2], bfr[4];
#pragma unroll
    for (int mt = 0; mt < 2; ++mt)
      af[mt] = *(const bf16x8*)(ab + (wm + mt * 16 + l16) * 32 + rq);
#pragma unroll
    for (int nt = 0; nt < 4; ++nt)
      bfr[nt] = *(const bf16x8*)(bb + (wn + nt * 16 + l16) * 32 + rq);

    const bool more = (kt + 2 < 32);
    if (more) {
      const int wcIdx = (rc + 2 >= 3) ? rc - 1 : rc + 2;
      const int kc = (kt + 2) * 32;
      async16(Ag + kc,  As + wcIdx * OBA + sdst);
      async16(Wg0 + kc, Bs + wcIdx * OBB + sdst);
      async16(Wg1 + kc, Bs + wcIdx * OBB + OBA + sdst);
    }

    waitl0();

    __builtin_amdgcn_s_setprio(1);
#pragma unroll
    for (int mt = 0; mt < 2; ++mt)
#pragma unroll
      for (int nt = 0; nt < 4; ++nt)
        acc[mt][nt] = __builtin_amdgcn_mfma_f32_16x16x32_bf16(af[mt], bfr[nt], acc[mt][nt], 0, 0, 0);
    __builtin_amdgcn_s_setprio(0);

    if (kt < 31) {
      if (more) waitv3();
      else      waitv0();
      __builtin_amdgcn_s_barrier();
    }
    rc = (rc == 2) ? 0 : rc + 1;
  }
}

// ---------------- slow GEMM core (fp32 A converted on the fly) ----------------
__device__ __forceinline__ void gemm_tile_f32(const float* __restrict__ A,
                                              const unsigned short* __restrict__ W,
                                              int m0, int n0,
                                              short* As, short* Bs,
                                              f32x4 acc[4][4])
{
  const int t    = threadIdx.x;
  const int lane = t & 63;
  const int w    = t >> 6;
  const int quad = lane >> 4;
  const int l16  = lane & 15;
  const int wm   = (w >> 1) * 64;
  const int wn   = (w & 1) * 64;
  const int srow = t >> 2;
  const int scol = (t & 3) * 8;

  for (int mt = 0; mt < 4; ++mt)
    for (int nt = 0; nt < 4; ++nt)
      acc[mt][nt] = f32x4{0.f, 0.f, 0.f, 0.f};

  for (int kt = 0; kt < D_MODEL / 32; ++kt) {
    const int kc = kt * 32 + scol;
    const bf16x8 a0 = cvt8(A + (size_t)(m0 + srow)      * D_MODEL + kc);
    const bf16x8 a1 = cvt8(A + (size_t)(m0 + srow + 64) * D_MODEL + kc);
    const bf16x8 b0 = *(const bf16x8*)(W + (size_t)(n0 + srow)      * D_MODEL + kc);
    const bf16x8 b1 = *(const bf16x8*)(W + (size_t)(n0 + srow + 64) * D_MODEL + kc);
    __syncthreads();
    *(bf16x8*)(As + (srow)      * LDK + scol) = a0;
    *(bf16x8*)(As + (srow + 64) * LDK + scol) = a1;
    *(bf16x8*)(Bs + (srow)      * LDK + scol) = b0;
    *(bf16x8*)(Bs + (srow + 64) * LDK + scol) = b1;
    __syncthreads();

    bf16x8 af[4], bfr[4];
    for (int mt = 0; mt < 4; ++mt)
      af[mt] = *(const bf16x8*)(As + (wm + mt * 16 + l16) * LDK + quad * 8);
    for (int nt = 0; nt < 4; ++nt)
      bfr[nt] = *(const bf16x8*)(Bs + (wn + nt * 16 + l16) * LDK + quad * 8);
    for (int mt = 0; mt < 4; ++mt)
      for (int nt = 0; nt < 4; ++nt)
        acc[mt][nt] = __builtin_amdgcn_mfma_f32_16x16x32_bf16(af[mt], bfr[nt], acc[mt][nt], 0, 0, 0);
  }
}

// ---------------- QKV epilogue for the 8-wave 128x128 core -------------------
__device__ __forceinline__ void qkv_epilogue8w(int z, int m0, int n0,
                                               const float* __restrict__ bias,
                                               float scale,
                                               unsigned short* __restrict__ dst,
                                               f32x4 acc[4][2])
{
  const int t    = threadIdx.x;
  const int lane = t & 63;
  const int w    = t >> 6;
  const int quad = lane >> 4;
  const int l16  = lane & 15;
  const int wm   = (w >> 2) * 64;
  const int wn   = (w & 3) * 32;

  for (int nt = 0; nt < 2; ++nt) {
    const int n = n0 + wn + nt * 16 + l16;
    const float bb = bias[n];
    const int h = n >> 6, d = n & 63;
    for (int mt = 0; mt < 4; ++mt) {
      for (int r = 0; r < 4; ++r) {
        const int m = m0 + wm + mt * 16 + quad * 4 + r;
        const int b = m >> 11, s = m & 2047;
        const unsigned short val = f2bf((acc[mt][nt][r] + bb) * scale);
        if (z < 2)
          dst[((size_t)((b * NHEAD + h) * S_LEN + s)) * HEAD_DIM + d] = val;
        else
          dst[((size_t)((b * NHEAD + h) * HEAD_DIM + d)) * S_LEN + s] = val;
      }
    }
  }
}

// ---------------- QKV projection, fast (counted-vmcnt + swizzle) -------------
__global__ __launch_bounds__(512)
void qkv_fast(const unsigned short* __restrict__ qb,
              const unsigned short* __restrict__ kb,
              const unsigned short* __restrict__ vb,
              const unsigned short* __restrict__ wqb,
              const unsigned short* __restrict__ wkb,
              const unsigned short* __restrict__ wvb,
              const float* __restrict__ bq, const float* __restrict__ bk,
              const float* __restrict__ bv,
              unsigned short* __restrict__ Qh, unsigned short* __restrict__ Kh,
              unsigned short* __restrict__ VhT)
{
  __shared__ __attribute__((aligned(16))) short As[3 * QBUF];
  __shared__ __attribute__((aligned(16))) short Bs[3 * QBUF];
  const int z = blockIdx.z;
  const unsigned short* A    = (z == 0) ? qb  : (z == 1) ? kb  : vb;
  const unsigned short* W    = (z == 0) ? wqb : (z == 1) ? wkb : wvb;
  const float*          bias = (z == 0) ? bq  : (z == 1) ? bk  : bv;
  unsigned short*       dst  = (z == 0) ? Qh  : (z == 1) ? Kh  : VhT;
  const float           scale = (z == 0) ? Q_SCALE : 1.0f;

  const int m0 = blockIdx.x * 128, n0 = blockIdx.y * 128;
  f32x4 acc[4][2];
  gemm_tile_cv(A, W, m0, n0, As, Bs, acc);
  qkv_epilogue8w(z, m0, n0, bias, scale, dst, acc);
}

// ---------------- QKV projection, slow (fp32 inputs) ----------------
__global__ __launch_bounds__(256)
void qkv_slow(const float* __restrict__ query, const float* __restrict__ key,
              const float* __restrict__ value,
              const unsigned short* __restrict__ wqb,
              const unsigned short* __restrict__ wkb,
              const unsigned short* __restrict__ wvb,
              const float* __restrict__ bq, const float* __restrict__ bk,
              const float* __restrict__ bv,
              unsigned short* __restrict__ Qh, unsigned short* __restrict__ Kh,
              unsigned short* __restrict__ VhT)
{
  __shared__ __attribute__((aligned(16))) short As[128 * LDK];
  __shared__ __attribute__((aligned(16))) short Bs[128 * LDK];
  const int z = blockIdx.z;
  const float*          A    = (z == 0) ? query : (z == 1) ? key : value;
  const unsigned short* W    = (z == 0) ? wqb   : (z == 1) ? wkb : wvb;
  const float*          bias = (z == 0) ? bq    : (z == 1) ? bk  : bv;
  unsigned short*       dst  = (z == 0) ? Qh    : (z == 1) ? Kh  : VhT;
  const float           scale = (z == 0) ? Q_SCALE : 1.0f;

  const int m0 = blockIdx.x * 128, n0 = blockIdx.y * 128;
  f32x4 acc[4][4];
  gemm_tile_f32(A, W, m0, n0, As, Bs, acc);

  const int t    = threadIdx.x;
  const int lane = t & 63;
  const int w    = t >> 6;
  const int quad = lane >> 4;
  const int l16  = lane & 15;
  const int wm   = (w >> 1) * 64;
  const int wn   = (w & 1) * 64;
  for (int nt = 0; nt < 4; ++nt) {
    const int n = n0 + wn + nt * 16 + l16;
    const float bb = bias[n];
    const int h = n >> 6, d = n & 63;
    for (int mt = 0; mt < 4; ++mt) {
      for (int r = 0; r < 4; ++r) {
        const int m = m0 + wm + mt * 16 + quad * 4 + r;
        const int b = m >> 11, s = m & 2047;
        const unsigned short val = f2bf((acc[mt][nt][r] + bb) * scale);
        if (z < 2)
          dst[((size_t)((b * NHEAD + h) * S_LEN + s)) * HEAD_DIM + d] = val;
        else
          dst[((size_t)((b * NHEAD + h) * HEAD_DIM + d)) * S_LEN + s] = val;
      }
    }
  }
}

// ---------------- output projection: 64x128, counted-vmcnt + swizzle ---------
__global__ __launch_bounds__(256)
void out_proj(const unsigned short* __restrict__ Oh,
              const unsigned short* __restrict__ wob,
              const float* __restrict__ bo,
              float* __restrict__ dst)
{
  __shared__ __attribute__((aligned(16))) short As[3 * OBA];
  __shared__ __attribute__((aligned(16))) short Bs[3 * OBB];
  const int m0 = blockIdx.x * 64, n0 = blockIdx.y * 128;
  f32x4 acc[2][4];
  gemm_tile_cv64(Oh, wob, m0, n0, As, Bs, acc);

  const int t    = threadIdx.x;
  const int lane = t & 63;
  const int w    = t >> 6;
  const int quad = lane >> 4;
  const int l16  = lane & 15;
  const int wm   = (w >> 1) * 32;
  const int wn   = (w & 1) * 64;

  for (int nt = 0; nt < 4; ++nt) {
    const int n = n0 + wn + nt * 16 + l16;
    const float bb = bo[n];
    for (int mt = 0; mt < 2; ++mt)
      for (int r = 0; r < 4; ++r) {
        const int m = m0 + wm + mt * 16 + quad * 4 + r;
        dst[(size_t)m * D_MODEL + n] = acc[mt][nt][r] + bb;
      }
  }
}

// ---------------- causal flash attention v16: balanced qt pairing ------------
// The measured-best attn (43.0-43.4 us): 8-wave dbuf, T14 issue-early staging,
// setprio, swapped QK^T with in-register P transpose.
struct Frags { bf16x8 ka0, ka1, kb0, kb1, v0, v1, v2, v3; };
struct StageRegs { bf16x8 k0, k1, v0, v1; };

#define KS_LD 72    // padded stride (shorts) for Ks rows
#define VT_LD 136   // padded stride (shorts) for Vts rows

__device__ __forceinline__ StageRegs load_stage(const unsigned short* __restrict__ Kb,
                                                const unsigned short* __restrict__ Vb,
                                                int k0, int kr, int kc, int vd, int vc) {
  StageRegs r;
  r.k0 = *(const bf16x8*)(Kb + (size_t)(k0 + kr)      * HEAD_DIM + kc);
  r.k1 = *(const bf16x8*)(Kb + (size_t)(k0 + kr + 64) * HEAD_DIM + kc);
  r.v0 = *(const bf16x8*)(Vb + (size_t)(vd)      * S_LEN + k0 + vc);
  r.v1 = *(const bf16x8*)(Vb + (size_t)(vd + 32) * S_LEN + k0 + vc);
  return r;
}
__device__ __forceinline__ void write_stage(const StageRegs& r, short* Ks, short* Vts,
                                            int kr, int kc, int vd, int vc) {
  *(bf16x8*)(Ks + (kr)      * KS_LD + kc) = r.k0;
  *(bf16x8*)(Ks + (kr + 64) * KS_LD + kc) = r.k1;
  *(bf16x8*)(Vts + (vd)      * VT_LD + vc) = r.v0;
  *(bf16x8*)(Vts + (vd + 32) * VT_LD + vc) = r.v1;
}
__device__ __forceinline__ Frags lds_frags(const short* Ks, const short* Vts,
                                           int c, int quad, int l16) {
  Frags f;
  const short* kp = Ks + (c * 32 + l16) * KS_LD + quad * 8;
  f.ka0 = *(const bf16x8*)(kp);
  f.ka1 = *(const bf16x8*)(kp + 32);
  f.kb0 = *(const bf16x8*)(kp + 16 * KS_LD);
  f.kb1 = *(const bf16x8*)(kp + 16 * KS_LD + 32);
  const short* vp = Vts + l16 * VT_LD + c * 32 + quad * 8;
  f.v0 = *(const bf16x8*)(vp);
  f.v1 = *(const bf16x8*)(vp + 16 * VT_LD);
  f.v2 = *(const bf16x8*)(vp + 32 * VT_LD);
  f.v3 = *(const bf16x8*)(vp + 48 * VT_LD);
  return f;
}

// One 32-k chunk for a 16-row wave. Swapped QK^T: s0/s1 hold k-halves
// [c0..c0+15] / [c0+16..c0+31] x q=l16. MODE: 0 = full; 1 = diag even-wave
// (s0 masked k<=q, s1 all-zero, its MFMAs skipped); 2 = diag odd-wave
// (s0 full, s1 masked). Masked predicate in both diag modes: quad*4+r <= l16.
template <int MODE>
__device__ __forceinline__ void proc_chunk(const Frags& f, const bf16x8 qf[2],
                                           const bf16x8& ones, int quad, int l16,
                                           f32x4& lacc, f32x4 oacc[4]) {
  f32x4 s0 = f32x4{0.f, 0.f, 0.f, 0.f};
  f32x4 s1 = f32x4{0.f, 0.f, 0.f, 0.f};
  __builtin_amdgcn_s_setprio(1);
  s0 = __builtin_amdgcn_mfma_f32_16x16x32_bf16(f.ka0, qf[0], s0, 0, 0, 0);
  s0 = __builtin_amdgcn_mfma_f32_16x16x32_bf16(f.ka1, qf[1], s0, 0, 0, 0);
  if (MODE != 1) {
    s1 = __builtin_amdgcn_mfma_f32_16x16x32_bf16(f.kb0, qf[0], s1, 0, 0, 0);
    s1 = __builtin_amdgcn_mfma_f32_16x16x32_bf16(f.kb1, qf[1], s1, 0, 0, 0);
  }
  __builtin_amdgcn_s_setprio(0);

  float st0[4], st1[4];
  const int kl = quad * 4;
#pragma unroll
  for (int r = 0; r < 4; ++r) {
    if (MODE == 0) {
      st0[r] = fexp2(s0[r]);
      st1[r] = fexp2(s1[r]);
    } else if (MODE == 1) {
      st0[r] = (kl + r <= l16) ? fexp2(s0[r]) : 0.f;
      st1[r] = 0.f;
    } else {
      st0[r] = fexp2(s0[r]);
      st1[r] = (kl + r <= l16) ? fexp2(s1[r]) : 0.f;
    }
  }

  // A-frag: P[q=l16][k = c0 + quad*8 + 0..7]  (verified pack+swap net)
  unsigned int a = pkbf(st0[0], st0[1]), b = pkbf(st0[2], st0[3]);
  unsigned int c = pkbf(st1[0], st1[1]), e = pkbf(st1[2], st1[3]);
  swap32(a, c); swap32(b, e);
  swap16(a, c); swap16(b, e);
  union { unsigned int u[4]; bf16x8 v; } pf;
  pf.u[0] = a; pf.u[1] = b; pf.u[2] = c; pf.u[3] = e;

  __builtin_amdgcn_s_setprio(1);
  lacc = __builtin_amdgcn_mfma_f32_16x16x32_bf16(pf.v, ones, lacc, 0, 0, 0);
  oacc[0] = __builtin_amdgcn_mfma_f32_16x16x32_bf16(pf.v, f.v0, oacc[0], 0, 0, 0);
  oacc[1] = __builtin_amdgcn_mfma_f32_16x16x32_bf16(pf.v, f.v1, oacc[1], 0, 0, 0);
  oacc[2] = __builtin_amdgcn_mfma_f32_16x16x32_bf16(pf.v, f.v2, oacc[2], 0, 0, 0);
  oacc[3] = __builtin_amdgcn_mfma_f32_16x16x32_bf16(pf.v, f.v3, oacc[3], 0, 0, 0);
  __builtin_amdgcn_s_setprio(0);
}

__global__ __launch_bounds__(512, 4)
void attn_kernel(const unsigned short* __restrict__ Qh,
                 const unsigned short* __restrict__ Kh,
                 const unsigned short* __restrict__ VhT,
                 unsigned short* __restrict__ O)
{
  __shared__ __attribute__((aligned(16))) short Ks[2][128 * KS_LD];
  __shared__ __attribute__((aligned(16))) short Vts[2][64 * VT_LD];

  // XCD swizzle (4 heads/XCD) + balanced qt map: qt(i) + qt(i+256) = 15.
  const int orig = blockIdx.x;
  const int xcd  = orig & 7;
  const int li   = orig >> 3;          // 0..63
  const int bh   = xcd * 4 + (li & 3);
  const int j16  = li >> 2;            // 0..15
  const int qt   = (j16 < 8) ? (15 - j16) : (j16 - 8);
  const int q0   = qt * 128;
  const int b    = bh >> 4;
  const int h    = bh & 15;
  const int t    = threadIdx.x;        // 0..511
  const int w    = t >> 6;             // 0..7 (wave id)
  const int lane = t & 63;
  const int quad = lane >> 4;
  const int l16  = lane & 15;
  const int rowbase = q0 + w * 16;     // wave owns 16 q-rows

  const unsigned short* Kb = Kh + (size_t)bh * S_LEN * HEAD_DIM;
  const unsigned short* Vb = VhT + (size_t)bh * HEAD_DIM * S_LEN;
  const int kr = t >> 3, kc = (t & 7) * 8;     // K staging: 512 thr x 2 rows
  const int vd = t >> 4, vc = (t & 15) * 8;    // V staging: 512 thr x 2 rows

  bf16x8 qf[2];
  {
    const size_t qrow = (size_t)bh * S_LEN + rowbase + l16;
    qf[0] = *(const bf16x8*)(Qh + qrow * HEAD_DIM + quad * 8);
    qf[1] = *(const bf16x8*)(Qh + qrow * HEAD_DIM + 32 + quad * 8);
  }
  bf16x8 ones;
#pragma unroll
  for (int j = 0; j < 8; ++j) ones[j] = (short)0x3F80;

  f32x4 lacc = f32x4{0.f, 0.f, 0.f, 0.f};
  f32x4 oacc[4];
#pragma unroll
  for (int dt = 0; dt < 4; ++dt) oacc[dt] = f32x4{0.f, 0.f, 0.f, 0.f};

  // Tiles 0..qt of 128 k. Tile j<qt: 4 full chunks. Tile qt: wave w does
  // (w>>1) full chunks + 1 diag chunk (mode by parity of w).
  const int nT = qt + 1;
  const int cw = w >> 1;
  const bool odd = (w & 1) != 0;

  StageRegs rs = load_stage(Kb, Vb, 0, kr, kc, vd, vc);
  write_stage(rs, Ks[0], Vts[0], kr, kc, vd, vc);
  __syncthreads();
  for (int j = 0; j < nT; ++j) {
    const short* Ksj = (j & 1) ? Ks[1] : Ks[0];
    const short* Vtj = (j & 1) ? Vts[1] : Vts[0];
    short* Ksn = (j & 1) ? Ks[0] : Ks[1];
    short* Vtn = (j & 1) ? Vts[0] : Vts[1];
    const bool more = (j + 1 < nT);
    if (more) rs = load_stage(Kb, Vb, (j + 1) * 128, kr, kc, vd, vc);  // T14
    if (j < qt) {
#pragma unroll
      for (int c = 0; c < 4; ++c) {
        const Frags f = lds_frags(Ksj, Vtj, c, quad, l16);
        proc_chunk<0>(f, qf, ones, quad, l16, lacc, oacc);
      }
    } else {
      for (int c = 0; c < cw; ++c) {         // wave-uniform bound
        const Frags f = lds_frags(Ksj, Vtj, c, quad, l16);
        proc_chunk<0>(f, qf, ones, quad, l16, lacc, oacc);
      }
      const Frags f = lds_frags(Ksj, Vtj, cw, quad, l16);
      if (odd) proc_chunk<2>(f, qf, ones, quad, l16, lacc, oacc);
      else     proc_chunk<1>(f, qf, ones, quad, l16, lacc, oacc);
    }
    if (more) write_stage(rs, Ksn, Vtn, kr, kc, vd, vc);
    __syncthreads();
  }

#pragma unroll
  for (int dt = 0; dt < 4; ++dt)
#pragma unroll
    for (int r = 0; r < 4; ++r) {
      const int rowg = rowbase + quad * 4 + r;
      O[(size_t)(b * S_LEN + rowg) * D_MODEL + h * 64 + dt * 16 + l16] =
          f2bf(oacc[dt][r] / lacc[r]);
    }
}

// ---------------- launcher ----------------
// ws layout: [0,8M) wqb|wkb|wvb|wob ; [8,16M) Kh ; [16,24M) VhT ;
//            [24,32M) qb (dead after qkv) then Oh ; [32,40M) vb (fast only)
// d_out: [0,8M) Qh bf16 scratch ; [8,16M) kb bf16 scratch; out_proj writes last.
extern "C" void kernel_launch(void* const* d_in, const int* in_sizes, int n_in,
                              void* d_out, int out_size, void* d_ws, size_t ws_size,
                              hipStream_t stream)
{
  (void)in_sizes; (void)n_in; (void)out_size;
  const float* q  = (const float*)d_in[0];
  const float* k  = (const float*)d_in[1];
  const float* v  = (const float*)d_in[2];
  const float* wq = (const float*)d_in[3];
  const float* bq = (const float*)d_in[4];
  const float* wk = (const float*)d_in[5];
  const float* bk = (const float*)d_in[6];
  const float* wv = (const float*)d_in[7];
  const float* bv = (const float*)d_in[8];
  const float* wo = (const float*)d_in[9];
  const float* bo = (const float*)d_in[10];
  float* out = (float*)d_out;

  unsigned short* wb  = (unsigned short*)d_ws;
  unsigned short* wqb = wb;
  unsigned short* wkb = wb + (size_t)1 * D_MODEL * D_MODEL;
  unsigned short* wvb = wb + (size_t)2 * D_MODEL * D_MODEL;
  unsigned short* wob = wb + (size_t)3 * D_MODEL * D_MODEL;
  unsigned short* Kh  = wb + (size_t)4 * D_MODEL * D_MODEL;
  unsigned short* VhT = Kh + (size_t)M_TOT * D_MODEL;
  unsigned short* Oh  = VhT + (size_t)M_TOT * D_MODEL;
  unsigned short* qb  = Oh;
  unsigned short* vb  = Oh + (size_t)M_TOT * D_MODEL;
  unsigned short* Qh  = (unsigned short*)d_out;
  unsigned short* kb  = Qh + (size_t)M_TOT * D_MODEL;

  const bool fast = ws_size >= (size_t)40 * 1024 * 1024;

  if (fast) {
    dim3 gc((size_t)M_TOT * D_MODEL / (256 * 8), 7, 1);
    cast_all<<<gc, 256, 0, stream>>>(wq, wk, wv, wo, q, k, v, wb, qb, kb, vb);
    dim3 g1(M_TOT / 128, D_MODEL / 128, 3);
    qkv_fast<<<g1, 512, 0, stream>>>(qb, kb, vb, wqb, wkb, wvb, bq, bk, bv, Qh, Kh, VhT);
  } else {
    dim3 gc((size_t)D_MODEL * D_MODEL / (256 * 8), 4, 1);
    cast_all<<<gc, 256, 0, stream>>>(wq, wk, wv, wo, q, k, v, wb, qb, kb, vb);
    dim3 g1(M_TOT / 128, D_MODEL / 128, 3);
    qkv_slow<<<g1, 256, 0, stream>>>(q, k, v, wqb, wkb, wvb, bq, bk, bv, Qh, Kh, VhT);
  }

  dim3 g2(512, 1, 1);
  attn_kernel<<<g2, 512, 0, stream>>>(Qh, Kh, VhT, Oh);

  dim3 g3(M_TOT / 64, D_MODEL / 128, 1);
  out_proj<<<g3, 256, 0, stream>>>(Oh, wob, bo, out);
}